// Round 2
// baseline (275.649 us; speedup 1.0000x reference)
//
#include <hip/hip_runtime.h>
#include <hip/hip_bf16.h>
#include <stdint.h>

// KAN layer: out[b,k] = sum_{i,j} B_j(x[b,i]) * W[k,i,j] + bias[k]
// batch=4096, in_features=512, out_features=512, num_basis=30, order=3
// Strategy: materialize basis as bf16 A[4096, 15360]; W flat [512,15360] cast
// to bf16 (already K-major "B^T" layout); bf16 MFMA GEMM, split-K=2, fp32
// atomicAdd into bias-initialized d_out.

#define BATCH 4096
#define INF   512
#define OUTF  512
#define NB    30
#define NKNOT 34
#define KDIM  (INF * NB)   // 15360

#define BM 128
#define BN 128
#define BK 32
#define KSPLIT 2
#define KHALF (KDIM / KSPLIT)     // 7680
#define NSTEP (KHALF / BK)        // 240

typedef short v8s __attribute__((ext_vector_type(8)));   // 8 bf16 as shorts (4 VGPRs)
typedef float v4f __attribute__((ext_vector_type(4)));

__device__ __forceinline__ unsigned short f2bf(float f) {
  uint32_t u = __float_as_uint(f);
  uint32_t r = (u + 0x7fffu + ((u >> 16) & 1u)) >> 16;
  return (unsigned short)r;
}

// ---------------- kernel 1: W fp32 -> bf16 (layout preserved) ----------------
__global__ __launch_bounds__(256) void w_cast_kernel(const float* __restrict__ in,
                                                     unsigned short* __restrict__ out) {
  int idx = blockIdx.x * 256 + threadIdx.x;       // one per 8 elements
  const float4* p = (const float4*)in + (size_t)idx * 2;
  float4 a = p[0];
  float4 b = p[1];
  uint4 o;
  o.x = (uint32_t)f2bf(a.x) | ((uint32_t)f2bf(a.y) << 16);
  o.y = (uint32_t)f2bf(a.z) | ((uint32_t)f2bf(a.w) << 16);
  o.z = (uint32_t)f2bf(b.x) | ((uint32_t)f2bf(b.y) << 16);
  o.w = (uint32_t)f2bf(b.z) | ((uint32_t)f2bf(b.w) << 16);
  *((uint4*)(out + (size_t)idx * 8)) = o;
}

// ---------------- kernel 2: basis materialization -----------------------------
// thread <-> (b, i). Local Cox-de Boor (NURBS book A2.2): only 4 nonzero basis
// values B_{m-3..m}^3 for t[m] <= x < t[m+1]. valid iff x in [t[3], t[30]].
__global__ __launch_bounds__(256) void basis_kernel(const float* __restrict__ x,
                                                    const float* __restrict__ knots,
                                                    unsigned short* __restrict__ A) {
  __shared__ uint32_t sbuf[256 * 15];
  int tid = threadIdx.x;
  int idx = blockIdx.x * 256 + tid;               // b*512 + i
  int fi  = idx & (INF - 1);
  const float* t = knots + (size_t)fi * NKNOT;
  float xv = x[idx];
  float N0 = 0.f, N1 = 0.f, N2 = 0.f, N3 = 0.f;
  int m = 3;
  float tlo = t[3], thi = t[30];
  if (xv >= tlo && xv <= thi) {
    float t0 = t[0];
    float h  = t[1] - t0;
    m = (int)floorf((xv - t0) / h);
    m = m < 3 ? 3 : (m > 30 ? 30 : m);
    while (m > 3 && xv < t[m]) --m;
    while (m < 30 && xv >= t[m + 1]) ++m;
    float Nv[4], left[4], right[4];
    Nv[0] = 1.f;
    #pragma unroll
    for (int d = 1; d <= 3; ++d) {
      left[d]  = xv - t[m + 1 - d];
      right[d] = t[m + d] - xv;
      float saved = 0.f;
      #pragma unroll
      for (int r = 0; r < d; ++r) {
        float temp = Nv[r] / (right[r + 1] + left[d - r]);
        Nv[r] = saved + right[r + 1] * temp;
        saved = left[d - r] * temp;
      }
      Nv[d] = saved;
    }
    N0 = Nv[0]; N1 = Nv[1]; N2 = Nv[2]; N3 = Nv[3];
  }
  int j0 = m - 3;   // basis index of N0
  #pragma unroll
  for (int dw = 0; dw < 15; ++dw) {
    int ja = dw * 2, jb = dw * 2 + 1;
    float va = (ja == j0) ? N0 : (ja == j0 + 1) ? N1 : (ja == j0 + 2) ? N2 : (ja == j0 + 3) ? N3 : 0.f;
    float vb = (jb == j0) ? N0 : (jb == j0 + 1) ? N1 : (jb == j0 + 2) ? N2 : (jb == j0 + 3) ? N3 : 0.f;
    sbuf[tid * 15 + dw] = (uint32_t)f2bf(va) | ((uint32_t)f2bf(vb) << 16);
  }
  __syncthreads();
  // block's output region is contiguous: 256 threads * 30 bf16 = 3840 dwords
  uint32_t* dst = (uint32_t*)(A + (size_t)blockIdx.x * 256 * NB);
  #pragma unroll
  for (int k = 0; k < 15; ++k)
    dst[k * 256 + tid] = sbuf[k * 256 + tid];
}

// ---------------- kernel 3: bias init -----------------------------------------
__global__ __launch_bounds__(256) void bias_kernel(const float* __restrict__ bias,
                                                   float* __restrict__ out) {
  int idx = blockIdx.x * 256 + threadIdx.x;
  out[idx] = bias[idx & (OUTF - 1)];
}

// ---------------- kernel 4: bf16 MFMA GEMM, split-K=2, atomic epilogue --------
// C[M,N] += A[M,K] * Bt[N,K]^T ; 128x128 tile, 4 waves (2x2), each wave 64x64
__global__ __launch_bounds__(256, 2) void gemm_kernel(const unsigned short* __restrict__ A,
                                                      const unsigned short* __restrict__ Bt,
                                                      float* __restrict__ C) {
  __shared__ unsigned short As[BM * BK];
  __shared__ unsigned short Bs[BN * BK];
  int tid  = threadIdx.x;
  int lane = tid & 63;
  int wave = tid >> 6;
  int bm = blockIdx.x >> 2;
  int bn = blockIdx.x & 3;
  int ks = blockIdx.y;

  int row0 = bm * BM;
  int col0 = bn * BN;
  int kk0  = ks * KHALF;

  // staging: each thread loads 2x 16B (rows tid>>2 and tid>>2 + 64, k-seg tid&3)
  int srow = tid >> 2;
  int seg  = tid & 3;
  const unsigned short* aptr0 = A  + (size_t)(row0 + srow) * KDIM + kk0 + seg * 8;
  const unsigned short* aptr1 = aptr0 + (size_t)64 * KDIM;
  const unsigned short* bptr0 = Bt + (size_t)(col0 + srow) * KDIM + kk0 + seg * 8;
  const unsigned short* bptr1 = bptr0 + (size_t)64 * KDIM;
  uint32_t soff = srow * BK + seg * 8;

  v4f acc[4][4];
  #pragma unroll
  for (int i = 0; i < 4; ++i)
    #pragma unroll
    for (int j = 0; j < 4; ++j)
      acc[i][j] = (v4f){0.f, 0.f, 0.f, 0.f};

  int wr  = (wave >> 1) & 1;
  int wc  = wave & 1;
  int r16 = lane & 15;
  int kg  = lane >> 4;
  uint32_t a_off0 = (uint32_t)(wr * 64 + r16) * BK + kg * 8;
  uint32_t b_off0 = (uint32_t)(wc * 64 + r16) * BK + kg * 8;

  uint4 ar0 = *(const uint4*)aptr0;
  uint4 ar1 = *(const uint4*)aptr1;
  uint4 br0 = *(const uint4*)bptr0;
  uint4 br1 = *(const uint4*)bptr1;

  for (int t = 0; t < NSTEP; ++t) {
    __syncthreads();
    *(uint4*)&As[soff]           = ar0;
    *(uint4*)&As[soff + 64 * BK] = ar1;
    *(uint4*)&Bs[soff]           = br0;
    *(uint4*)&Bs[soff + 64 * BK] = br1;
    __syncthreads();
    if (t + 1 < NSTEP) {
      aptr0 += BK; aptr1 += BK; bptr0 += BK; bptr1 += BK;
      ar0 = *(const uint4*)aptr0;
      ar1 = *(const uint4*)aptr1;
      br0 = *(const uint4*)bptr0;
      br1 = *(const uint4*)bptr1;
    }
    v8s af[4], bfr[4];
    #pragma unroll
    for (int mi = 0; mi < 4; ++mi)
      af[mi] = *(const v8s*)&As[a_off0 + (uint32_t)mi * 16 * BK];
    #pragma unroll
    for (int ni = 0; ni < 4; ++ni)
      bfr[ni] = *(const v8s*)&Bs[b_off0 + (uint32_t)ni * 16 * BK];
    #pragma unroll
    for (int mi = 0; mi < 4; ++mi)
      #pragma unroll
      for (int ni = 0; ni < 4; ++ni)
        acc[mi][ni] = __builtin_amdgcn_mfma_f32_16x16x32_bf16(af[mi], bfr[ni], acc[mi][ni], 0, 0, 0);
  }

  // epilogue: C/D layout col=lane&15, row=(lane>>4)*4+reg  [m89/m91]
  int crow = (lane >> 4) * 4;
  int ccol = lane & 15;
  #pragma unroll
  for (int mi = 0; mi < 4; ++mi) {
    #pragma unroll
    for (int ni = 0; ni < 4; ++ni) {
      int r = row0 + wr * 64 + mi * 16 + crow;
      int c = col0 + wc * 64 + ni * 16 + ccol;
      #pragma unroll
      for (int q = 0; q < 4; ++q)
        atomicAdd(&C[(size_t)(r + q) * OUTF + c], acc[mi][ni][q]);
    }
  }
}

extern "C" void kernel_launch(void* const* d_in, const int* in_sizes, int n_in,
                              void* d_out, int out_size, void* d_ws, size_t ws_size,
                              hipStream_t stream) {
  const float* x     = (const float*)d_in[0];
  const float* knots = (const float*)d_in[1];
  const float* W     = (const float*)d_in[2];
  const float* bias  = (const float*)d_in[3];
  float* out = (float*)d_out;

  // workspace layout: Wt bf16 [512*15360] (15.7 MB) then A bf16 [4096*15360] (125.8 MB)
  unsigned short* Wt = (unsigned short*)d_ws;
  unsigned short* Ab = (unsigned short*)d_ws + (size_t)OUTF * KDIM;

  w_cast_kernel<<<(OUTF * KDIM / 8) / 256, 256, 0, stream>>>(W, Wt);
  basis_kernel<<<(BATCH * INF) / 256, 256, 0, stream>>>(x, knots, Ab);
  bias_kernel<<<(BATCH * OUTF) / 256, 256, 0, stream>>>(bias, out);
  gemm_kernel<<<dim3((BATCH / BM) * (OUTF / BN), KSPLIT), 256, 0, stream>>>(Ab, Wt, out);
}

// Round 3
// 239.135 us; speedup vs baseline: 1.1527x; 1.1527x over previous
//
#include <hip/hip_runtime.h>
#include <hip/hip_bf16.h>
#include <stdint.h>

// KAN layer: out[b,k] = sum_{i,j} B_j(x[b,i]) * W[k,i,j] + bias[k]
// batch=4096, in=512, out=512, num_basis=30, order=3
// GEMM view: M=4096, N=512, K=15360; A=basis bf16, Bt=W bf16 (native [N][K]).
// This round: m97-structure GEMM (global_load_lds w=16, BK=64, XOR-swizzled LDS
// via pre-swizzled source, split-K=6 -> 3 blocks/CU, XCD-chunked block order).

#define BATCH 4096
#define INF   512
#define OUTF  512
#define NB    30
#define NKNOT 34
#define KDIM  (INF * NB)          // 15360

#define BM 128
#define BN 128
#define BK 64
#define KSPLIT 6
#define KCHUNK (KDIM / KSPLIT)    // 2560
#define NSTEP  (KCHUNK / BK)      // 40

typedef short v8s __attribute__((ext_vector_type(8)));   // 8 bf16 (4 VGPRs)
typedef float v4f __attribute__((ext_vector_type(4)));

__device__ __forceinline__ unsigned short f2bf(float f) {
  uint32_t u = __float_as_uint(f);
  uint32_t r = (u + 0x7fffu + ((u >> 16) & 1u)) >> 16;
  return (unsigned short)r;
}

// CK-style addrspace casts (inttoptr — compiles on all ROCm clangs; LDS
// aperture is 4GB-aligned so low 32 bits of a generic LDS pointer are the
// workgroup LDS offset).
__device__ __forceinline__ void gload16(const unsigned short* g, unsigned short* l) {
  auto gp = reinterpret_cast<const __attribute__((address_space(1))) unsigned short*>(
      reinterpret_cast<uintptr_t>(g));
  auto lp = reinterpret_cast<__attribute__((address_space(3))) unsigned short*>(
      reinterpret_cast<uintptr_t>(l));
  __builtin_amdgcn_global_load_lds(gp, lp, 16, 0, 0);
}

// ---------------- kernel 1: W fp32 -> bf16 (layout preserved) ----------------
__global__ __launch_bounds__(256) void w_cast_kernel(const float* __restrict__ in,
                                                     unsigned short* __restrict__ out) {
  int idx = blockIdx.x * 256 + threadIdx.x;       // one per 8 elements
  const float4* p = (const float4*)in + (size_t)idx * 2;
  float4 a = p[0];
  float4 b = p[1];
  uint4 o;
  o.x = (uint32_t)f2bf(a.x) | ((uint32_t)f2bf(a.y) << 16);
  o.y = (uint32_t)f2bf(a.z) | ((uint32_t)f2bf(a.w) << 16);
  o.z = (uint32_t)f2bf(b.x) | ((uint32_t)f2bf(b.y) << 16);
  o.w = (uint32_t)f2bf(b.z) | ((uint32_t)f2bf(b.w) << 16);
  *((uint4*)(out + (size_t)idx * 8)) = o;
}

// ---------------- kernel 2: basis materialization -----------------------------
// Local Cox-de Boor (NURBS A2.2): 4 nonzeros B_{m-3..m}^3 for t[m]<=x<t[m+1].
// Zero-fill 15 dwords then pack the 4 nonzeros into 2-3 dwords directly.
__global__ __launch_bounds__(256) void basis_kernel(const float* __restrict__ x,
                                                    const float* __restrict__ knots,
                                                    unsigned short* __restrict__ A) {
  __shared__ uint32_t sbuf[256 * 15];
  int tid = threadIdx.x;
  int idx = blockIdx.x * 256 + tid;               // b*512 + i
  int fi  = idx & (INF - 1);
  const float* t = knots + (size_t)fi * NKNOT;
  float xv = x[idx];
  #pragma unroll
  for (int d = 0; d < 15; ++d) sbuf[tid * 15 + d] = 0;
  float tlo = t[3], thi = t[30];
  if (xv >= tlo && xv <= thi) {
    float t0v = t[0];
    float h   = t[1] - t0v;
    int m = (int)floorf((xv - t0v) / h);
    m = m < 3 ? 3 : (m > 30 ? 30 : m);
    while (m > 3 && xv < t[m]) --m;
    while (m < 30 && xv >= t[m + 1]) ++m;
    float Nv[4], left[4], right[4];
    Nv[0] = 1.f;
    #pragma unroll
    for (int d = 1; d <= 3; ++d) {
      left[d]  = xv - t[m + 1 - d];
      right[d] = t[m + d] - xv;
      float saved = 0.f;
      #pragma unroll
      for (int r = 0; r < d; ++r) {
        float temp = Nv[r] / (right[r + 1] + left[d - r]);
        Nv[r] = saved + right[r + 1] * temp;
        saved = left[d - r] * temp;
      }
      Nv[d] = saved;
    }
    int j0 = m - 3;                 // 0..27
    int d0 = j0 >> 1;
    uint32_t* s = &sbuf[tid * 15];
    if (j0 & 1) {
      s[d0] = (uint32_t)f2bf(Nv[0]) << 16;
      s[d0 + 1] = (uint32_t)f2bf(Nv[1]) | ((uint32_t)f2bf(Nv[2]) << 16);
      if (d0 + 2 < 15) s[d0 + 2] = (uint32_t)f2bf(Nv[3]);
    } else {
      s[d0] = (uint32_t)f2bf(Nv[0]) | ((uint32_t)f2bf(Nv[1]) << 16);
      if (d0 + 1 < 15) s[d0 + 1] = (uint32_t)f2bf(Nv[2]) | ((uint32_t)f2bf(Nv[3]) << 16);
    }
  }
  __syncthreads();
  // linear copy of the block's contiguous 3840-dword region, coalesced
  uint32_t* dst = (uint32_t*)(A + (size_t)blockIdx.x * 256 * NB);
  #pragma unroll
  for (int k = 0; k < 15; ++k)
    dst[k * 256 + tid] = sbuf[k * 256 + tid];
}

// ---------------- kernel 3: bias init -----------------------------------------
__global__ __launch_bounds__(256) void bias_kernel(const float* __restrict__ bias,
                                                   float* __restrict__ out) {
  int idx = blockIdx.x * 256 + threadIdx.x;
  out[idx] = bias[idx & (OUTF - 1)];
}

// ---------------- kernel 4: MFMA GEMM, gload_lds + swizzle, split-K=6 ---------
// LDS tile layout: [row][slot] with slot = seg ^ (row&7)  (seg = 16B column).
// gload_lds writes linearly; the swizzle is realized by pre-swizzling the
// per-lane GLOBAL source address (rule #21); ds_read applies the same XOR.
__global__ __launch_bounds__(256, 3) void gemm_kernel(const unsigned short* __restrict__ A,
                                                      const unsigned short* __restrict__ Bt,
                                                      float* __restrict__ C) {
  __shared__ unsigned short As[BM * BK];   // 16 KB
  __shared__ unsigned short Bs[BN * BK];   // 16 KB
  int tid  = threadIdx.x;
  int lane = tid & 63;
  int w    = tid >> 6;

  // XCD-chunked bijective swizzle (768 % 8 == 0): XCD gets 96 consecutive swz;
  // bn-major order -> each XCD's blocks share one 3.9MB W panel (fits L2).
  int bid = blockIdx.x;
  int swz = (bid & 7) * 96 + (bid >> 3);
  int bn  = swz / 192;
  int rem = swz - bn * 192;
  int bm  = rem / 6;
  int ks  = rem - bm * 6;

  int row0 = bm * BM;
  int col0 = bn * BN;
  int kk0  = ks * KCHUNK;

  // staging source: lane l covers (row = w*8 + (l>>3), seg_swz = (l&7)^(l>>3))
  int lrow = lane >> 3;
  int lseg = (lane & 7) ^ lrow;
  const unsigned short* ga = A  + (size_t)(row0 + w * 8 + lrow) * KDIM + kk0 + lseg * 8;
  const unsigned short* gb = Bt + (size_t)(col0 + w * 8 + lrow) * KDIM + kk0 + lseg * 8;
  unsigned short* lA = &As[w * 512];
  unsigned short* lB = &Bs[w * 512];

  v4f acc[4][4];
  #pragma unroll
  for (int i = 0; i < 4; ++i)
    #pragma unroll
    for (int j = 0; j < 4; ++j)
      acc[i][j] = (v4f){0.f, 0.f, 0.f, 0.f};

  int wr  = (w >> 1) & 1;
  int wc  = w & 1;
  int r16 = lane & 15;
  int kg  = lane >> 4;
  unsigned xr   = (unsigned)(r16 & 7);
  unsigned s0   = ((unsigned)kg ^ xr) * 16;          // kc=0 slot byte offset
  unsigned aoff = (unsigned)(wr * 64 + r16) * 128;   // row byte offset in As
  unsigned boff = (unsigned)(wc * 64 + r16) * 128;
  const char* Ab = (const char*)As;
  const char* Bb = (const char*)Bs;

  for (int t = 0; t < NSTEP; ++t) {
    #pragma unroll
    for (int q = 0; q < 4; ++q) {
      gload16(ga + (size_t)q * (32 * KDIM), lA + q * 2048);
      gload16(gb + (size_t)q * (32 * KDIM), lB + q * 2048);
    }
    ga += BK; gb += BK;
    __syncthreads();            // drains vmcnt: tile ready
    #pragma unroll
    for (int kc = 0; kc < 2; ++kc) {
      unsigned sk = s0 ^ (kc * 64);
      v8s af[4], bf[4];
      #pragma unroll
      for (int mi = 0; mi < 4; ++mi)
        af[mi] = *(const v8s*)(Ab + aoff + mi * 2048 + sk);
      #pragma unroll
      for (int ni = 0; ni < 4; ++ni)
        bf[ni] = *(const v8s*)(Bb + boff + ni * 2048 + sk);
      #pragma unroll
      for (int mi = 0; mi < 4; ++mi)
        #pragma unroll
        for (int ni = 0; ni < 4; ++ni)
          acc[mi][ni] = __builtin_amdgcn_mfma_f32_16x16x32_bf16(af[mi], bf[ni], acc[mi][ni], 0, 0, 0);
    }
    __syncthreads();            // compute done: safe to overwrite LDS
  }

  // epilogue: C/D layout col=lane&15, row=(lane>>4)*4+reg  [m89/m91]
  int crow = (lane >> 4) * 4;
  int ccol = lane & 15;
  #pragma unroll
  for (int mi = 0; mi < 4; ++mi) {
    #pragma unroll
    for (int ni = 0; ni < 4; ++ni) {
      int r = row0 + wr * 64 + mi * 16 + crow;
      int c = col0 + wc * 64 + ni * 16 + ccol;
      #pragma unroll
      for (int q = 0; q < 4; ++q)
        atomicAdd(&C[(size_t)(r + q) * OUTF + c], acc[mi][ni][q]);
    }
  }
}

extern "C" void kernel_launch(void* const* d_in, const int* in_sizes, int n_in,
                              void* d_out, int out_size, void* d_ws, size_t ws_size,
                              hipStream_t stream) {
  const float* x     = (const float*)d_in[0];
  const float* knots = (const float*)d_in[1];
  const float* W     = (const float*)d_in[2];
  const float* bias  = (const float*)d_in[3];
  float* out = (float*)d_out;

  // workspace: Wt bf16 [512*15360] (15.7 MB) then A bf16 [4096*15360] (125.8 MB)
  unsigned short* Wt = (unsigned short*)d_ws;
  unsigned short* Ab = (unsigned short*)d_ws + (size_t)OUTF * KDIM;

  w_cast_kernel<<<(OUTF * KDIM / 8) / 256, 256, 0, stream>>>(W, Wt);
  basis_kernel<<<(BATCH * INF) / 256, 256, 0, stream>>>(x, knots, Ab);
  bias_kernel<<<(BATCH * OUTF) / 256, 256, 0, stream>>>(bias, out);
  gemm_kernel<<<(BATCH / BM) * (OUTF / BN) * KSPLIT, 256, 0, stream>>>(Ab, Wt, out);
}

// Round 4
// 232.743 us; speedup vs baseline: 1.1843x; 1.0275x over previous
//
#include <hip/hip_runtime.h>
#include <hip/hip_bf16.h>
#include <stdint.h>

// KAN layer: out[b,k] = sum_{i,j} B_j(x[b,i]) * W[k,i,j] + bias[k]
// batch=4096, in=512, out=512, num_basis=30 (padded to 32), order=3
// GEMM view: M=4096, N=512, K'=512*32=16384. A (basis) is FUSED: computed
// per K-step into swizzled LDS (never hits HBM). B = W cast to bf16, padded
// 30->32 cols per feature. 2-phase double-buffered MFMA loop, split-K=4.

#define BATCH 4096
#define INF   512
#define OUTF  512
#define NB    30
#define NBP   32                   // padded basis cols per feature
#define NKNOT 34
#define KDIMP (INF * NBP)          // 16384

#define BM 128
#define BN 128
#define BK 64                      // 2 features per K-step
#define KSPLIT 4
#define KCHUNK (KDIMP / KSPLIT)    // 4096 -> 128 features per block
#define NT     (KCHUNK / BK)       // 64 K-steps

typedef short v8s __attribute__((ext_vector_type(8)));   // 8 bf16 (4 VGPRs)
typedef float v4f __attribute__((ext_vector_type(4)));

__device__ __forceinline__ unsigned short f2bf(float f) {
  uint32_t u = __float_as_uint(f);
  uint32_t r = (u + 0x7fffu + ((u >> 16) & 1u)) >> 16;
  return (unsigned short)r;
}

__device__ __forceinline__ void gload16(const unsigned short* g, unsigned short* l) {
  auto gp = reinterpret_cast<const __attribute__((address_space(1))) unsigned short*>(
      reinterpret_cast<uintptr_t>(g));
  auto lp = reinterpret_cast<__attribute__((address_space(3))) unsigned short*>(
      reinterpret_cast<uintptr_t>(l));
  __builtin_amdgcn_global_load_lds(gp, lp, 16, 0, 0);
}

// ---------------- kernel 1: W fp32 -> bf16, pad 30 -> 32 cols ----------------
// one thread per output dword (2 padded cols): out[k][i*32 + 2jp .. 2jp+1]
__global__ __launch_bounds__(256) void w_cast_kernel(const float* __restrict__ in,
                                                     unsigned short* __restrict__ out) {
  int idx = blockIdx.x * 256 + threadIdx.x;       // dword index, 512*8192 total
  int k   = idx >> 13;                            // 8192 dwords per out row
  int rem = idx & 8191;
  int i   = rem >> 4;
  int jp  = rem & 15;
  int j   = jp * 2;
  const float* src = in + ((size_t)k * INF + i) * NB;
  float lo = (j     < NB) ? src[j]     : 0.f;
  float hi = (j + 1 < NB) ? src[j + 1] : 0.f;
  ((uint32_t*)out)[idx] = (uint32_t)f2bf(lo) | ((uint32_t)f2bf(hi) << 16);
}

// ---------------- kernel 2: x transpose  xT[f][b] = x[b][f] ------------------
__global__ __launch_bounds__(256) void xt_kernel(const float* __restrict__ x,
                                                 float* __restrict__ xT) {
  __shared__ float tile[32][33];
  int b0 = blockIdx.x * 32;
  int f0 = blockIdx.y * 32;
  int lx = threadIdx.x & 31;
  int ly = threadIdx.x >> 5;                      // 8 rows per pass
  #pragma unroll
  for (int q = 0; q < 4; ++q)
    tile[ly + q * 8][lx] = x[(size_t)(b0 + ly + q * 8) * INF + f0 + lx];
  __syncthreads();
  #pragma unroll
  for (int q = 0; q < 4; ++q)
    xT[(size_t)(f0 + ly + q * 8) * BATCH + b0 + lx] = tile[lx][ly + q * 8];
}

// ---------------- kernel 3: bias init ----------------------------------------
__global__ __launch_bounds__(256) void bias_kernel(const float* __restrict__ bias,
                                                   float* __restrict__ out) {
  int idx = blockIdx.x * 256 + threadIdx.x;
  out[idx] = bias[idx & (OUTF - 1)];
}

// ---------------- fused basis eval -> swizzled LDS ---------------------------
// Thread owns (row b, feature-half hf): zeros its 64B (4 swizzled 16B slots),
// then packs the 4 nonzero cubic B-spline values (Cox-de Boor A2.2).
__device__ __forceinline__ void evalA(unsigned short* Abuf, int b, int hf,
                                      float xv, const float* __restrict__ tk) {
  unsigned rowb = (unsigned)b * 128;              // 64 cols * 2B
  unsigned x7   = (unsigned)(b & 7);
  char* base = (char*)Abuf;
  uint4 z = {0u, 0u, 0u, 0u};
  #pragma unroll
  for (int s = 0; s < 4; ++s) {
    unsigned slot = ((unsigned)(hf * 4 + s)) ^ x7;
    *(uint4*)(base + rowb + (slot << 4)) = z;
  }
  float tlo = tk[3], thi = tk[30];
  if (!(xv >= tlo && xv <= thi)) return;
  float t0v = tk[0];
  float h   = tk[1] - t0v;
  int m = (int)floorf((xv - t0v) * __builtin_amdgcn_rcpf(h));
  m = m < 3 ? 3 : (m > 30 ? 30 : m);
  while (m > 3 && xv < tk[m]) --m;
  while (m < 30 && xv >= tk[m + 1]) ++m;
  float Nv[4], left[4], right[4];
  Nv[0] = 1.f;
  #pragma unroll
  for (int d = 1; d <= 3; ++d) {
    left[d]  = xv - tk[m + 1 - d];
    right[d] = tk[m + d] - xv;
    float saved = 0.f;
    #pragma unroll
    for (int r = 0; r < d; ++r) {
      float temp = Nv[r] * __builtin_amdgcn_rcpf(right[r + 1] + left[d - r]);
      Nv[r] = saved + right[r + 1] * temp;
      saved = left[d - r] * temp;
    }
    Nv[d] = saved;
  }
  int j0 = m - 3;                                 // 0..27
  int d0 = (hf * 16) + (j0 >> 1);                 // dword index in row (0..31)
  // swizzled dword store helper (inline): byte=(d*4); slot=byte>>4 ^ x7
  #define WR32(d, v) { unsigned by = (unsigned)(d) * 4u; \
    *(uint32_t*)(base + rowb + ((((by >> 4) ^ x7) << 4) | (by & 15u))) = (v); }
  if (j0 & 1) {
    WR32(d0,     (uint32_t)f2bf(Nv[0]) << 16);
    WR32(d0 + 1, (uint32_t)f2bf(Nv[1]) | ((uint32_t)f2bf(Nv[2]) << 16));
    WR32(d0 + 2, (uint32_t)f2bf(Nv[3]));
  } else {
    WR32(d0,     (uint32_t)f2bf(Nv[0]) | ((uint32_t)f2bf(Nv[1]) << 16));
    WR32(d0 + 1, (uint32_t)f2bf(Nv[2]) | ((uint32_t)f2bf(Nv[3]) << 16));
  }
  #undef WR32
}

// ---------------- kernel 4: fused GEMM ---------------------------------------
__global__ __launch_bounds__(256, 2) void gemm_kernel(const float* __restrict__ xT,
                                                      const float* __restrict__ knots,
                                                      const unsigned short* __restrict__ Bt,
                                                      float* __restrict__ C) {
  __shared__ unsigned short As[2][BM * BK];   // 2 x 16 KB
  __shared__ unsigned short Bs[2][BN * BK];   // 2 x 16 KB
  int tid  = threadIdx.x;
  int lane = tid & 63;
  int w    = tid >> 6;

  // XCD-chunked bijective swizzle (512 % 8 == 0), bn-major for L2 W reuse
  int bid = blockIdx.x;
  int swz = (bid & 7) * 64 + (bid >> 3);
  int bn  = swz >> 7;                  // /128
  int rem = swz & 127;
  int bm  = rem >> 2;
  int ks  = rem & 3;

  int row0 = bm * BM;
  int col0 = bn * BN;
  int kk0  = ks * KCHUNK;
  int fbase = kk0 / NBP;               // first feature of this K-chunk

  // eval mapping: thread -> (row eb, feature-half hf)
  int eb = tid & 127;
  int hf = tid >> 7;

  // B staging source (pre-swizzled global addr, linear LDS dest)
  int lrow = lane >> 3;
  int lseg = (lane & 7) ^ lrow;
  const unsigned short* gb = Bt + (size_t)(col0 + w * 8 + lrow) * KDIMP + kk0 + lseg * 8;
  unsigned short* lBbase[2] = { &Bs[0][w * 512], &Bs[1][w * 512] };

  v4f acc[4][4];
  #pragma unroll
  for (int i = 0; i < 4; ++i)
    #pragma unroll
    for (int j = 0; j < 4; ++j)
      acc[i][j] = (v4f){0.f, 0.f, 0.f, 0.f};

  int wr  = (w >> 1) & 1;
  int wc  = w & 1;
  int r16 = lane & 15;
  int kg  = lane >> 4;
  unsigned s0   = ((unsigned)kg ^ (unsigned)(r16 & 7)) << 4;
  unsigned aoff = (unsigned)(wr * 64 + r16) * 128;
  unsigned boff = (unsigned)(wc * 64 + r16) * 128;

  // ---- prologue: stage tile 0 into buf 0
  float xv_s = xT[(size_t)(fbase + hf) * BATCH + row0 + eb];
  {
    #pragma unroll
    for (int q = 0; q < 4; ++q)
      gload16(gb + (size_t)q * (32 * KDIMP), lBbase[0] + q * 2048);
    evalA(As[0], eb, hf, xv_s, knots + (size_t)(fbase + hf) * NKNOT);
  }
  xv_s = xT[(size_t)(fbase + 2 + hf) * BATCH + row0 + eb];   // for t=1 stage
  __syncthreads();

  for (int t = 0; t < NT; ++t) {
    int c = t & 1;
    if (t + 1 < NT) {
      const unsigned short* src = gb + (size_t)(t + 1) * BK;
      #pragma unroll
      for (int q = 0; q < 4; ++q)
        gload16(src + (size_t)q * (32 * KDIMP), lBbase[c ^ 1] + q * 2048);
      int f = fbase + 2 * (t + 1) + hf;
      evalA(As[c ^ 1], eb, hf, xv_s, knots + (size_t)f * NKNOT);
    }
    float xv_n = 0.f;
    if (t + 2 < NT)
      xv_n = xT[(size_t)(fbase + 2 * (t + 2) + hf) * BATCH + row0 + eb];

    const char* Ab = (const char*)As[c];
    const char* Bb = (const char*)Bs[c];
    #pragma unroll
    for (int kc = 0; kc < 2; ++kc) {
      unsigned sk = s0 ^ (unsigned)(kc << 6);
      v8s af[4], bf[4];
      #pragma unroll
      for (int mi = 0; mi < 4; ++mi)
        af[mi] = *(const v8s*)(Ab + aoff + mi * 2048 + sk);
      #pragma unroll
      for (int ni = 0; ni < 4; ++ni)
        bf[ni] = *(const v8s*)(Bb + boff + ni * 2048 + sk);
      #pragma unroll
      for (int mi = 0; mi < 4; ++mi)
        #pragma unroll
        for (int ni = 0; ni < 4; ++ni)
          acc[mi][ni] = __builtin_amdgcn_mfma_f32_16x16x32_bf16(af[mi], bf[ni], acc[mi][ni], 0, 0, 0);
    }
    __syncthreads();
    xv_s = xv_n;
  }

  // epilogue: C/D layout col=lane&15, row=(lane>>4)*4+reg  [m89/m91]
  int crow = (lane >> 4) * 4;
  int ccol = lane & 15;
  #pragma unroll
  for (int mi = 0; mi < 4; ++mi) {
    #pragma unroll
    for (int ni = 0; ni < 4; ++ni) {
      int r = row0 + wr * 64 + mi * 16 + crow;
      int c = col0 + wc * 64 + ni * 16 + ccol;
      #pragma unroll
      for (int q = 0; q < 4; ++q)
        atomicAdd(&C[(size_t)(r + q) * OUTF + c], acc[mi][ni][q]);
    }
  }
}

extern "C" void kernel_launch(void* const* d_in, const int* in_sizes, int n_in,
                              void* d_out, int out_size, void* d_ws, size_t ws_size,
                              hipStream_t stream) {
  const float* x     = (const float*)d_in[0];
  const float* knots = (const float*)d_in[1];
  const float* W     = (const float*)d_in[2];
  const float* bias  = (const float*)d_in[3];
  float* out = (float*)d_out;

  // workspace: Wt bf16 [512][16384] (16.8 MB) then xT f32 [512][4096] (8.4 MB)
  unsigned short* Wt = (unsigned short*)d_ws;
  float*          xT = (float*)((char*)d_ws + (size_t)OUTF * KDIMP * 2);

  w_cast_kernel<<<(OUTF * KDIMP / 2) / 256, 256, 0, stream>>>(W, Wt);
  xt_kernel<<<dim3(BATCH / 32, INF / 32), 256, 0, stream>>>(x, xT);
  bias_kernel<<<(BATCH * OUTF) / 256, 256, 0, stream>>>(bias, out);
  gemm_kernel<<<(BATCH / BM) * (OUTF / BN) * KSPLIT, 256, 0, stream>>>(xT, knots, Wt, out);
}

// Round 5
// 197.504 us; speedup vs baseline: 1.3957x; 1.1784x over previous
//
#include <hip/hip_runtime.h>
#include <hip/hip_bf16.h>
#include <stdint.h>

// KAN layer: out[b,k] = sum_{i,j} B_j(x[b,i]) * W[k,i,j] + bias[k]
// batch=4096, in=512, out=512, num_basis=30 (padded to 32), order=3
// GEMM view: M=4096, N=512, K'=16384. Basis is sparse (4 nonzeros/feature):
// precomputed compactly (valsT 4xbf16 + j0T byte, feature-major), expanded
// into swizzled LDS inside the GEMM. A never touches HBM.
// GEMM: single-buffer 2-barrier, gload_lds B, KSPLIT=8 -> 4 blocks/CU.

#define BATCH 4096
#define INF   512
#define OUTF  512
#define NB    30
#define NBP   32
#define NKNOT 34
#define KDIMP (INF * NBP)          // 16384

#define BM 128
#define BN 128
#define BK 64                      // 2 features per K-step
#define KSPLIT 8
#define KCHUNK (KDIMP / KSPLIT)    // 2048
#define NT     (KCHUNK / BK)       // 32
#define FPC    (KCHUNK / NBP)      // 64 features per chunk

typedef short v8s __attribute__((ext_vector_type(8)));
typedef float v4f __attribute__((ext_vector_type(4)));

__device__ __forceinline__ unsigned short f2bf(float f) {
  uint32_t u = __float_as_uint(f);
  uint32_t r = (u + 0x7fffu + ((u >> 16) & 1u)) >> 16;
  return (unsigned short)r;
}

__device__ __forceinline__ void gload16(const unsigned short* g, unsigned short* l) {
  auto gp = reinterpret_cast<const __attribute__((address_space(1))) unsigned short*>(
      reinterpret_cast<uintptr_t>(g));
  auto lp = reinterpret_cast<__attribute__((address_space(3))) unsigned short*>(
      reinterpret_cast<uintptr_t>(l));
  __builtin_amdgcn_global_load_lds(gp, lp, 16, 0, 0);
}

// ---------------- kernel 1: W fp32 -> bf16, pad 30 -> 32 cols ----------------
__global__ __launch_bounds__(256) void w_cast_kernel(const float* __restrict__ in,
                                                     unsigned short* __restrict__ out) {
  int idx = blockIdx.x * 256 + threadIdx.x;       // dword index
  int k   = idx >> 13;
  int rem = idx & 8191;
  int i   = rem >> 4;
  int jp  = rem & 15;
  int j   = jp * 2;
  const float* src = in + ((size_t)k * INF + i) * NB;
  float lo = (j     < NB) ? src[j]     : 0.f;
  float hi = (j + 1 < NB) ? src[j + 1] : 0.f;
  ((uint32_t*)out)[idx] = (uint32_t)f2bf(lo) | ((uint32_t)f2bf(hi) << 16);
}

// ---------------- kernel 2: sparse basis precompute --------------------------
// valsT[f][b] = (N0,N1,N2,N3) packed bf16; j0T[f][b] = first nonzero basis idx.
// 32x32 LDS transpose tile: x read coalesced, valsT/j0T written coalesced.
__global__ __launch_bounds__(256) void basis_kernel(const float* __restrict__ x,
                                                    const float* __restrict__ knots,
                                                    uint2* __restrict__ valsT,
                                                    unsigned char* __restrict__ j0T) {
  __shared__ float tile[32][33];
  int b0 = blockIdx.x * 32;
  int f0 = blockIdx.y * 32;
  int lx = threadIdx.x & 31;
  int ly = threadIdx.x >> 5;                      // 0..7
  #pragma unroll
  for (int q = 0; q < 4; ++q)
    tile[ly + q * 8][lx] = x[(size_t)(b0 + ly + q * 8) * INF + f0 + lx]; // [b][f]
  __syncthreads();
  #pragma unroll
  for (int q = 0; q < 4; ++q) {
    int fy = ly + q * 8;                          // feature within tile
    float xv = tile[lx][fy];                      // b = lx
    const float* tk = knots + (size_t)(f0 + fy) * NKNOT;
    uint2 pv = {0u, 0u};
    int j0 = 0;
    float tlo = tk[3], thi = tk[30];
    if (xv >= tlo && xv <= thi) {
      float t0v = tk[0];
      float h   = tk[1] - t0v;
      int m = (int)floorf((xv - t0v) * __builtin_amdgcn_rcpf(h));
      m = m < 3 ? 3 : (m > 30 ? 30 : m);
      while (m > 3 && xv < tk[m]) --m;
      while (m < 30 && xv >= tk[m + 1]) ++m;
      float Nv[4], left[4], right[4];
      Nv[0] = 1.f;
      #pragma unroll
      for (int d = 1; d <= 3; ++d) {
        left[d]  = xv - tk[m + 1 - d];
        right[d] = tk[m + d] - xv;
        float saved = 0.f;
        #pragma unroll
        for (int r = 0; r < d; ++r) {
          float temp = Nv[r] * __builtin_amdgcn_rcpf(right[r + 1] + left[d - r]);
          Nv[r] = saved + right[r + 1] * temp;
          saved = left[d - r] * temp;
        }
        Nv[d] = saved;
      }
      j0 = m - 3;                                 // 0..27
      pv.x = (uint32_t)f2bf(Nv[0]) | ((uint32_t)f2bf(Nv[1]) << 16);
      pv.y = (uint32_t)f2bf(Nv[2]) | ((uint32_t)f2bf(Nv[3]) << 16);
    }
    size_t oi = (size_t)(f0 + fy) * BATCH + b0 + lx;
    valsT[oi] = pv;
    j0T[oi]   = (unsigned char)j0;
  }
}

// ---------------- kernel 3: bias init ----------------------------------------
__global__ __launch_bounds__(256) void bias_kernel(const float* __restrict__ bias,
                                                   float* __restrict__ out) {
  int idx = blockIdx.x * 256 + threadIdx.x;
  out[idx] = bias[idx & (OUTF - 1)];
}

// ---------------- A-subtile expand: compact (v,j0) -> swizzled LDS -----------
// Thread owns (row eb, feature-half hf): zero 4 XOR-swizzled 16B slots, then
// write the 2-3 dwords holding the 4 nonzeros. Slot sets across the two
// threads of a row are disjoint (XOR within 0..7) -> race-free.
__device__ __forceinline__ void writeA(unsigned short* Abuf, int eb, int hf,
                                       uint2 v, int j0) {
  unsigned rowb = (unsigned)eb * 128;
  unsigned x7   = (unsigned)(eb & 7);
  char* base = (char*)Abuf;
  uint4 z = {0u, 0u, 0u, 0u};
  #pragma unroll
  for (int s = 0; s < 4; ++s) {
    unsigned slot = ((unsigned)(hf * 4 + s)) ^ x7;
    *(uint4*)(base + rowb + (slot << 4)) = z;
  }
  int d0 = hf * 16 + (j0 >> 1);
  #define WR32(d, val) { unsigned by = (unsigned)(d) * 4u; \
    *(uint32_t*)(base + rowb + ((((by >> 4) ^ x7) << 4) | (by & 15u))) = (val); }
  if (j0 & 1) {
    WR32(d0,     v.x << 16);                      // (0, N0)
    WR32(d0 + 1, (v.x >> 16) | (v.y << 16));      // (N1, N2)
    WR32(d0 + 2, v.y >> 16);                      // (N3, 0)
  } else {
    WR32(d0,     v.x);                            // (N0, N1)
    WR32(d0 + 1, v.y);                            // (N2, N3)
  }
  #undef WR32
}

// ---------------- kernel 4: fused GEMM ---------------------------------------
__global__ __launch_bounds__(256, 4) void gemm_kernel(const uint2* __restrict__ valsT,
                                                      const unsigned char* __restrict__ j0T,
                                                      const unsigned short* __restrict__ Bt,
                                                      float* __restrict__ C) {
  __shared__ unsigned short As[BM * BK];   // 16 KB
  __shared__ unsigned short Bs[BN * BK];   // 16 KB
  int tid  = threadIdx.x;
  int lane = tid & 63;
  int w    = tid >> 6;

  // XCD-chunked bijective swizzle (1024 blocks, 128/XCD); ks,bm inner so an
  // XCD's blocks share a 2 MB W window in L2.
  int bid = blockIdx.x;
  int swz = (bid & 7) * 128 + (bid >> 3);
  int bn  = swz >> 8;                  // 4
  int rem = swz & 255;
  int ks  = rem >> 5;                  // 8
  int bm  = rem & 31;                  // 32

  int row0 = bm * BM;
  int col0 = bn * BN;
  int kk0  = ks * KCHUNK;
  int fbase = ks * FPC;

  // A expand mapping
  int eb = tid & 127;
  int hf = tid >> 7;
  size_t vidx0 = (size_t)(fbase + hf) * BATCH + row0 + eb;   // +8192 per step

  // B staging (pre-swizzled global source, linear LDS dest)
  int lrow = lane >> 3;
  int lseg = (lane & 7) ^ lrow;
  const unsigned short* gb = Bt + (size_t)(col0 + w * 8 + lrow) * KDIMP + kk0 + lseg * 8;
  unsigned short* lB = &Bs[w * 512];

  v4f acc[4][4];
  #pragma unroll
  for (int i = 0; i < 4; ++i)
    #pragma unroll
    for (int j = 0; j < 4; ++j)
      acc[i][j] = (v4f){0.f, 0.f, 0.f, 0.f};

  int wr  = (w >> 1) & 1;
  int wc  = w & 1;
  int r16 = lane & 15;
  int kg  = lane >> 4;
  unsigned s0   = ((unsigned)kg ^ (unsigned)(r16 & 7)) << 4;
  unsigned aoff = (unsigned)(wr * 64 + r16) * 128;
  unsigned boff = (unsigned)(wc * 64 + r16) * 128;

  // prologue: stage tile 0; preload (v,j) for tile 1
  uint2 vc = valsT[vidx0];
  int   jc = j0T[vidx0];
  writeA(As, eb, hf, vc, jc);
  #pragma unroll
  for (int q = 0; q < 4; ++q)
    gload16(gb + (size_t)q * (32 * KDIMP), lB + q * 2048);
  uint2 vn = valsT[vidx0 + 8192];
  int   jn = j0T[vidx0 + 8192];
  __syncthreads();

  for (int t = 0; t < NT; ++t) {
    // issue (v,j) loads for t+2 before MFMA cluster (latency hidden)
    uint2 v2 = {0u, 0u};
    int   j2 = 0;
    if (t + 2 < NT) {
      size_t ix = vidx0 + (size_t)(t + 2) * 8192;
      v2 = valsT[ix];
      j2 = j0T[ix];
    }
    const char* Ab = (const char*)As;
    const char* Bb = (const char*)Bs;
    #pragma unroll
    for (int kc = 0; kc < 2; ++kc) {
      unsigned sk = s0 ^ (unsigned)(kc << 6);
      v8s af[4], bf[4];
      #pragma unroll
      for (int mi = 0; mi < 4; ++mi)
        af[mi] = *(const v8s*)(Ab + aoff + mi * 2048 + sk);
      #pragma unroll
      for (int ni = 0; ni < 4; ++ni)
        bf[ni] = *(const v8s*)(Bb + boff + ni * 2048 + sk);
      #pragma unroll
      for (int mi = 0; mi < 4; ++mi)
        #pragma unroll
        for (int ni = 0; ni < 4; ++ni)
          acc[mi][ni] = __builtin_amdgcn_mfma_f32_16x16x32_bf16(af[mi], bf[ni], acc[mi][ni], 0, 0, 0);
    }
    __syncthreads();                 // LDS free
    if (t + 1 < NT) {
      writeA(As, eb, hf, vn, jn);
      const unsigned short* src = gb + (size_t)(t + 1) * BK;
      #pragma unroll
      for (int q = 0; q < 4; ++q)
        gload16(src + (size_t)q * (32 * KDIMP), lB + q * 2048);
      vn = v2; jn = j2;
      __syncthreads();               // tile t+1 ready
    }
  }

  // epilogue: C/D layout col=lane&15, row=(lane>>4)*4+reg  [m89/m91]
  int crow = (lane >> 4) * 4;
  int ccol = lane & 15;
  #pragma unroll
  for (int mi = 0; mi < 4; ++mi) {
    #pragma unroll
    for (int ni = 0; ni < 4; ++ni) {
      int r = row0 + wr * 64 + mi * 16 + crow;
      int c = col0 + wc * 64 + ni * 16 + ccol;
      #pragma unroll
      for (int q = 0; q < 4; ++q)
        atomicAdd(&C[(size_t)(r + q) * OUTF + c], acc[mi][ni][q]);
    }
  }
}

extern "C" void kernel_launch(void* const* d_in, const int* in_sizes, int n_in,
                              void* d_out, int out_size, void* d_ws, size_t ws_size,
                              hipStream_t stream) {
  const float* x     = (const float*)d_in[0];
  const float* knots = (const float*)d_in[1];
  const float* W     = (const float*)d_in[2];
  const float* bias  = (const float*)d_in[3];
  float* out = (float*)d_out;

  // ws: Wt bf16 [512][16384] (16 MB) | valsT uint2 [512][4096] (16 MB) | j0T (2 MB)
  unsigned short* Wt    = (unsigned short*)d_ws;
  uint2*          valsT = (uint2*)((char*)d_ws + (size_t)OUTF * KDIMP * 2);
  unsigned char*  j0T   = (unsigned char*)((char*)d_ws + (size_t)OUTF * KDIMP * 2
                                           + (size_t)INF * BATCH * 8);

  w_cast_kernel<<<(OUTF * KDIMP / 2) / 256, 256, 0, stream>>>(W, Wt);
  basis_kernel<<<dim3(BATCH / 32, INF / 32), 256, 0, stream>>>(x, knots, valsT, j0T);
  bias_kernel<<<(BATCH * OUTF) / 256, 256, 0, stream>>>(bias, out);
  gemm_kernel<<<(BATCH / BM) * (OUTF / BN) * KSPLIT, 256, 0, stream>>>(valsT, j0T, Wt, out);
}